// Round 14
// baseline (218.253 us; speedup 1.0000x reference)
//
#include <hip/hip_runtime.h>
#include <hip/hip_bf16.h>
#include <hip/hip_cooperative_groups.h>

namespace cg = cooperative_groups;

// score = sigmoid(relu([h[src]|h[dst]]@W1 + b1) @ W2 + b2)
// R14: ONE cooperative kernel. Phase A: uv[n]=[h@W1a+b1 | h@W1b] bf16
// (grid-strided wave-units, MFMA 32x32x16, direct W1 reads). threadfence +
// grid.sync (device-scope => cross-XCD safe). Phase B: R8 edge gather tail.
// Rationale: 6 different K1 structures all left a ~29us invisible residual;
// fusing makes the producer measurable (single dispatch in top-5) and, if the
// work is as small as arithmetic says (~5us), removes ~20us.

#define HID    128
#define NNODE  50000
#define NEDGE  600000
#define NGRP   1563                     // ceil(50000/32)
#define NAU    (NGRP * 8)               // phase-A units: group x colhalf x ct
#define FTPB   512
#define FGRID  768                      // 3 blocks/CU x 256 CU (clamped live)
#define K2BLK  2048
#define UVBYTES ((size_t)NNODE * 256 * 2)   // 25.6 MB

typedef __attribute__((ext_vector_type(8)))  __bf16 bf16x8;
typedef __attribute__((ext_vector_type(16))) float  f32x16;

static __device__ __forceinline__ unsigned int pack2bf(float a, float b) {
    unsigned int ua = __float_as_uint(a);
    unsigned int ub = __float_as_uint(b);
    ua = (ua + 0x7FFFu + ((ua >> 16) & 1u)) >> 16;
    ub = (ub + 0x7FFFu + ((ub >> 16) & 1u)) >> 16;
    return (ub << 16) | (ua & 0xFFFFu);
}

// ---------------- fused cooperative kernel ----------------
__global__ __launch_bounds__(FTPB, 3) void fused_kernel(
    const float* __restrict__ h,  const float* __restrict__ W1,
    const float* __restrict__ b1, const float* __restrict__ W2,
    const float* __restrict__ b2, const int* __restrict__ src,
    const int* __restrict__ dst,  float* __restrict__ out,
    unsigned short* __restrict__ uvs)
{
    const int t = threadIdx.x, lane = t & 63, wv = t >> 6;
    const int l31 = lane & 31, l5 = lane >> 5;

    bool idx64;
    {
        unsigned long long m =
            __ballot((src[2 * lane + 1] == 0) && (dst[2 * lane + 1] == 0));
        idx64 = (m == ~0ULL);
    }

    const int gw = blockIdx.x * 8 + wv;          // global wave id
    const int NWAVES = gridDim.x * 8;

    // ============ phase A: node GEMM, 1 unit = 32 nodes x 32 cols ============
    for (int unit = gw; unit < NAU; unit += NWAVES) {
        const int group   = unit >> 3;
        const int sub     = unit & 7;
        const int colhalf = sub >> 2;            // 0 -> u cols, 1 -> v cols
        const int ct      = sub & 3;             // 32-col slice within half

        const int node  = group * 32 + l31;
        const int nodec = node < NNODE ? node : NNODE - 1;
        const float* hp = h + (size_t)nodec * HID + l5 * 8;
        const int n = ct * 32 + l31;
        const float b1v = (colhalf == 0) ? b1[n] : 0.0f;

        f32x16 acc;
#pragma unroll
        for (int r = 0; r < 16; ++r) acc[r] = 0.0f;

#pragma unroll
        for (int ks = 0; ks < 8; ++ks) {
            float4 f0 = *(const float4*)(hp + ks * 16);
            float4 f1 = *(const float4*)(hp + ks * 16 + 4);
            bf16x8 af;
            af[0] = (__bf16)f0.x; af[1] = (__bf16)f0.y;
            af[2] = (__bf16)f0.z; af[3] = (__bf16)f0.w;
            af[4] = (__bf16)f1.x; af[5] = (__bf16)f1.y;
            af[6] = (__bf16)f1.z; af[7] = (__bf16)f1.w;
            // B-frag direct from W1: for fixed j, 32 lanes span 128 B (2 lines)
            const float* wp = W1 + (size_t)(colhalf * 128 + ks * 16 + l5 * 8)
                                       * HID + n;
            bf16x8 bfg;
#pragma unroll
            for (int j = 0; j < 8; ++j) bfg[j] = (__bf16)wp[(size_t)j * HID];
            acc = __builtin_amdgcn_mfma_f32_32x32x16_bf16(af, bfg, acc, 0, 0, 0);
        }

        // C row rr=(r&3)+8*(r>>2)+4*l5 (node), col = colhalf*128 + ct*32 + l31
#pragma unroll
        for (int r = 0; r < 16; ++r) {
            float mine = acc[r] + b1v;
            float partner = __shfl_xor(mine, 1);
            if (!(l31 & 1)) {
                const int rr = (r & 3) + 8 * (r >> 2) + 4 * l5;
                const int nd = group * 32 + rr;
                if (nd < NNODE) {
                    *(unsigned int*)(uvs + (size_t)nd * 256 +
                                     colhalf * 128 + n) = pack2bf(mine, partner);
                }
            }
        }
    }

    // ============ grid barrier (device-scope fences for cross-XCD) ============
    __threadfence();
    cg::this_grid().sync();
    __threadfence();

    // ============ phase B: edge gather + tiny MLP tail (R8 logic) ============
    const int c = lane & 15;
    const int g = lane >> 4;
    float w2f[8];
#pragma unroll
    for (int j = 0; j < 8; ++j) w2f[j] = W2[c * 8 + j];
    const float b2s = b2[0];

    const int NQ = NEDGE / 4;
    for (int q0 = gw; q0 < NQ; q0 += 2 * NWAVES) {
        const int q1  = q0 + NWAVES;
        const int q1c = q1 < NQ ? q1 : NQ - 1;
        const int e0  = q0 * 4 + g;
        const int e1  = q1c * 4 + g;

        const int ns0 = idx64 ? src[2 * e0] : src[e0];
        const int nd0 = idx64 ? dst[2 * e0] : dst[e0];
        const int ns1 = idx64 ? src[2 * e1] : src[e1];
        const int nd1 = idx64 ? dst[2 * e1] : dst[e1];

        const uint4 qu0 = *(const uint4*)(uvs + (size_t)ns0 * 256 + c * 8);
        const uint4 qv0 = *(const uint4*)(uvs + (size_t)nd0 * 256 + 128 + c * 8);
        const uint4 qu1 = *(const uint4*)(uvs + (size_t)ns1 * 256 + c * 8);
        const uint4 qv1 = *(const uint4*)(uvs + (size_t)nd1 * 256 + 128 + c * 8);

#pragma unroll
        for (int half = 0; half < 2; ++half) {
            const uint4 qu = half ? qu1 : qu0;
            const uint4 qv = half ? qv1 : qv0;
            float p = 0.0f;
#pragma unroll
            for (int j = 0; j < 4; ++j) {
                const unsigned int uw = j == 0 ? qu.x : j == 1 ? qu.y
                                      : j == 2 ? qu.z : qu.w;
                const unsigned int vw = j == 0 ? qv.x : j == 1 ? qv.y
                                      : j == 2 ? qv.z : qv.w;
                float slo = __uint_as_float(uw << 16)
                          + __uint_as_float(vw << 16);
                float shi = __uint_as_float(uw & 0xFFFF0000u)
                          + __uint_as_float(vw & 0xFFFF0000u);
                slo = slo > 0.0f ? slo : 0.0f;
                shi = shi > 0.0f ? shi : 0.0f;
                p = fmaf(slo, w2f[2 * j], p);
                p = fmaf(shi, w2f[2 * j + 1], p);
            }
            p += __shfl_xor(p, 1);
            p += __shfl_xor(p, 2);
            p += __shfl_xor(p, 4);
            p += __shfl_xor(p, 8);

            if (c == 0 && (half == 0 || q1 < NQ)) {
                const int e = half ? e1 : e0;
                out[e] = 1.0f / (1.0f + __expf(-(p + b2s)));
            }
        }
    }
}

// ---------------- fallback chain (R12, proven 72.3 us) ----------------
__global__ __launch_bounds__(256, 1) void node_gemm_kernel(
    const float* __restrict__ h, const float* __restrict__ W1,
    const float* __restrict__ b1, unsigned short* __restrict__ uvs)
{
    const int t = threadIdx.x, lane = t & 63, wv = t >> 6;
    const int l31 = lane & 31, l5 = lane >> 5;
    const int group = blockIdx.x * 2 + (wv >> 1);
    if (group >= NGRP) return;
    const int colhalf = wv & 1;
    float b1v[4];
#pragma unroll
    for (int ct = 0; ct < 4; ++ct)
        b1v[ct] = (colhalf == 0) ? b1[ct * 32 + l31] : 0.0f;
    const int node  = group * 32 + l31;
    const int nodec = node < NNODE ? node : NNODE - 1;
    const float* hp = h + (size_t)nodec * HID + l5 * 8;
    f32x16 acc[4];
#pragma unroll
    for (int ct = 0; ct < 4; ++ct)
#pragma unroll
        for (int r = 0; r < 16; ++r) acc[ct][r] = 0.0f;
#pragma unroll
    for (int ks = 0; ks < 8; ++ks) {
        float4 f0 = *(const float4*)(hp + ks * 16);
        float4 f1 = *(const float4*)(hp + ks * 16 + 4);
        bf16x8 af;
        af[0] = (__bf16)f0.x; af[1] = (__bf16)f0.y;
        af[2] = (__bf16)f0.z; af[3] = (__bf16)f0.w;
        af[4] = (__bf16)f1.x; af[5] = (__bf16)f1.y;
        af[6] = (__bf16)f1.z; af[7] = (__bf16)f1.w;
        const int kb = colhalf * 128 + ks * 16 + l5 * 8;
#pragma unroll
        for (int ct = 0; ct < 4; ++ct) {
            const int n = ct * 32 + l31;
            const float* wp = W1 + (size_t)kb * HID + n;
            bf16x8 bfg;
#pragma unroll
            for (int j = 0; j < 8; ++j) bfg[j] = (__bf16)wp[(size_t)j * HID];
            acc[ct] = __builtin_amdgcn_mfma_f32_32x32x16_bf16(af, bfg,
                                                              acc[ct], 0, 0, 0);
        }
    }
#pragma unroll
    for (int ct = 0; ct < 4; ++ct) {
#pragma unroll
        for (int r = 0; r < 16; ++r) {
            float mine = acc[ct][r] + b1v[ct];
            float partner = __shfl_xor(mine, 1);
            if (!(l31 & 1)) {
                const int rr = (r & 3) + 8 * (r >> 2) + 4 * l5;
                const int nd = group * 32 + rr;
                if (nd < NNODE) {
                    const int n = colhalf * 128 + ct * 32 + l31;
                    *(unsigned int*)(uvs + (size_t)nd * 256 + n) =
                        pack2bf(mine, partner);
                }
            }
        }
    }
}

__global__ __launch_bounds__(256, 8) void edge_score_kernel(
    const unsigned short* __restrict__ uvs,
    const float* __restrict__ W2, const float* __restrict__ b2,
    const int* __restrict__ src, const int* __restrict__ dst,
    float* __restrict__ out)
{
    const int t = threadIdx.x, lane = t & 63, wv = t >> 6;
    const int c = lane & 15;
    const int g = lane >> 4;
    bool idx64;
    {
        unsigned long long m =
            __ballot((src[2 * lane + 1] == 0) && (dst[2 * lane + 1] == 0));
        idx64 = (m == ~0ULL);
    }
    float w2f[8];
#pragma unroll
    for (int j = 0; j < 8; ++j) w2f[j] = W2[c * 8 + j];
    const float b2s = b2[0];
    const int gw = blockIdx.x * 4 + wv;
    const int NW = K2BLK * 4;
    const int NQ = NEDGE / 4;
    for (int q0 = gw; q0 < NQ; q0 += 2 * NW) {
        const int q1  = q0 + NW;
        const int q1c = q1 < NQ ? q1 : NQ - 1;
        const int e0  = q0 * 4 + g;
        const int e1  = q1c * 4 + g;
        const int ns0 = idx64 ? src[2 * e0] : src[e0];
        const int nd0 = idx64 ? dst[2 * e0] : dst[e0];
        const int ns1 = idx64 ? src[2 * e1] : src[e1];
        const int nd1 = idx64 ? dst[2 * e1] : dst[e1];
        const uint4 qu0 = *(const uint4*)(uvs + (size_t)ns0 * 256 + c * 8);
        const uint4 qv0 = *(const uint4*)(uvs + (size_t)nd0 * 256 + 128 + c * 8);
        const uint4 qu1 = *(const uint4*)(uvs + (size_t)ns1 * 256 + c * 8);
        const uint4 qv1 = *(const uint4*)(uvs + (size_t)nd1 * 256 + 128 + c * 8);
#pragma unroll
        for (int half = 0; half < 2; ++half) {
            const uint4 qu = half ? qu1 : qu0;
            const uint4 qv = half ? qv1 : qv0;
            float p = 0.0f;
#pragma unroll
            for (int j = 0; j < 4; ++j) {
                const unsigned int uw = j == 0 ? qu.x : j == 1 ? qu.y
                                      : j == 2 ? qu.z : qu.w;
                const unsigned int vw = j == 0 ? qv.x : j == 1 ? qv.y
                                      : j == 2 ? qv.z : qv.w;
                float slo = __uint_as_float(uw << 16)
                          + __uint_as_float(vw << 16);
                float shi = __uint_as_float(uw & 0xFFFF0000u)
                          + __uint_as_float(vw & 0xFFFF0000u);
                slo = slo > 0.0f ? slo : 0.0f;
                shi = shi > 0.0f ? shi : 0.0f;
                p = fmaf(slo, w2f[2 * j], p);
                p = fmaf(shi, w2f[2 * j + 1], p);
            }
            p += __shfl_xor(p, 1);
            p += __shfl_xor(p, 2);
            p += __shfl_xor(p, 4);
            p += __shfl_xor(p, 8);
            if (c == 0 && (half == 0 || q1 < NQ)) {
                const int e = half ? e1 : e0;
                out[e] = 1.0f / (1.0f + __expf(-(p + b2s)));
            }
        }
    }
}

extern "C" void kernel_launch(void* const* d_in, const int* in_sizes, int n_in,
                              void* d_out, int out_size, void* d_ws, size_t ws_size,
                              hipStream_t stream) {
    const float* h  = (const float*)d_in[0];
    const float* W1 = (const float*)d_in[1];
    const float* b1 = (const float*)d_in[2];
    const float* W2 = (const float*)d_in[3];
    const float* b2 = (const float*)d_in[4];
    const int* src  = (const int*)d_in[5];
    const int* dst  = (const int*)d_in[6];
    float* out = (float*)d_out;
    (void)in_sizes; (void)n_in; (void)out_size;

    if (ws_size < UVBYTES) return;   // ws guaranteed large; guard anyway
    unsigned short* uvs = (unsigned short*)d_ws;

    // co-residency-clamped cooperative grid (deterministic per-device)
    int maxBlk = 0;
    hipOccupancyMaxActiveBlocksPerMultiprocessor(&maxBlk,
        (const void*)fused_kernel, FTPB, 0);
    int grid = maxBlk * 256;                 // MI355X: 256 CUs
    if (grid > FGRID) grid = FGRID;
    hipError_t err = hipErrorUnknown;
    if (grid >= 1) {
        void* args[] = {(void*)&h, (void*)&W1, (void*)&b1, (void*)&W2,
                        (void*)&b2, (void*)&src, (void*)&dst, (void*)&out,
                        (void*)&uvs};
        err = hipLaunchCooperativeKernel((const void*)fused_kernel,
                                         dim3(grid), dim3(FTPB), args, 0,
                                         stream);
    }
    if (err != hipSuccess) {
        // fallback: proven R12 two-kernel chain
        node_gemm_kernel<<<(NGRP + 1) / 2, 256, 0, stream>>>(h, W1, b1, uvs);
        edge_score_kernel<<<K2BLK, 256, 0, stream>>>(uvs, W2, b2, src, dst,
                                                     out);
    }
}

// Round 15
// 79.466 us; speedup vs baseline: 2.7465x; 2.7465x over previous
//
#include <hip/hip_runtime.h>
#include <hip/hip_bf16.h>

// score = sigmoid(relu([h[src]|h[dst]]@W1 + b1) @ W2 + b2)
// R15: measurement round. K1 byte-identical to R12 (the ~25us mystery).
// K2 split into TWO half-range dispatches (~21.5us each) so K1 becomes the
// longest repeated dispatch and FINALLY gets rocprof counters (it has never
// appeared in the duration-sorted top-5; every K1 number so far is inference).
// R14 lesson: cooperative grid.sync on 768 blocks = 436us+ -> dead end.

#define HID    128
#define NNODE  50000
#define NEDGE  600000
#define NGRP   ((NNODE + 31) / 32)       // 1563 node groups of 32
#define K1BLK  ((NGRP + 1) / 2)          // 782 blocks, 2 groups (4 waves) each
#define K2BLK  1024                      // per half
#define NQ_ALL (NEDGE / 4)               // 150000 quads
#define NQ_HALF (NQ_ALL / 2)             // 75000
#define UVBYTES ((size_t)NNODE * 256 * 2)   // 25.6 MB

typedef __attribute__((ext_vector_type(8)))  __bf16 bf16x8;
typedef __attribute__((ext_vector_type(16))) float  f32x16;

static __device__ __forceinline__ unsigned int pack2bf(float a, float b) {
    unsigned int ua = __float_as_uint(a);
    unsigned int ub = __float_as_uint(b);
    ua = (ua + 0x7FFFu + ((ua >> 16) & 1u)) >> 16;
    ub = (ub + 0x7FFFu + ((ub >> 16) & 1u)) >> 16;
    return (ub << 16) | (ua & 0xFFFFu);
}

// ---------------- K1: node GEMM  uv[50000][256] bf16 (R12 exact) ----------------
__global__ __launch_bounds__(256, 1) void node_gemm_kernel(
    const float* __restrict__ h, const float* __restrict__ W1,
    const float* __restrict__ b1, unsigned short* __restrict__ uvs)
{
    const int t = threadIdx.x, lane = t & 63, wv = t >> 6;
    const int l31 = lane & 31, l5 = lane >> 5;

    const int group = blockIdx.x * 2 + (wv >> 1);
    if (group >= NGRP) return;
    const int colhalf = wv & 1;                 // 0 -> u cols, 1 -> v cols

    float b1v[4];
#pragma unroll
    for (int ct = 0; ct < 4; ++ct)
        b1v[ct] = (colhalf == 0) ? b1[ct * 32 + l31] : 0.0f;

    const int node  = group * 32 + l31;
    const int nodec = node < NNODE ? node : NNODE - 1;
    const float* hp = h + (size_t)nodec * HID + l5 * 8;

    f32x16 acc[4];
#pragma unroll
    for (int ct = 0; ct < 4; ++ct)
#pragma unroll
        for (int r = 0; r < 16; ++r) acc[ct][r] = 0.0f;

#pragma unroll
    for (int ks = 0; ks < 8; ++ks) {
        float4 f0 = *(const float4*)(hp + ks * 16);
        float4 f1 = *(const float4*)(hp + ks * 16 + 4);
        bf16x8 af;
        af[0] = (__bf16)f0.x; af[1] = (__bf16)f0.y;
        af[2] = (__bf16)f0.z; af[3] = (__bf16)f0.w;
        af[4] = (__bf16)f1.x; af[5] = (__bf16)f1.y;
        af[6] = (__bf16)f1.z; af[7] = (__bf16)f1.w;
        const int kb = colhalf * 128 + ks * 16 + l5 * 8;   // W1 row base
#pragma unroll
        for (int ct = 0; ct < 4; ++ct) {
            const int n = ct * 32 + l31;
            const float* wp = W1 + (size_t)kb * HID + n;
            bf16x8 bfg;
#pragma unroll
            for (int j = 0; j < 8; ++j) bfg[j] = (__bf16)wp[(size_t)j * HID];
            acc[ct] = __builtin_amdgcn_mfma_f32_32x32x16_bf16(af, bfg,
                                                              acc[ct], 0, 0, 0);
        }
    }

#pragma unroll
    for (int ct = 0; ct < 4; ++ct) {
#pragma unroll
        for (int r = 0; r < 16; ++r) {
            float mine = acc[ct][r] + b1v[ct];
            float partner = __shfl_xor(mine, 1);
            if (!(l31 & 1)) {
                const int rr = (r & 3) + 8 * (r >> 2) + 4 * l5;
                const int nd = group * 32 + rr;
                if (nd < NNODE) {
                    const int n = colhalf * 128 + ct * 32 + l31;
                    *(unsigned int*)(uvs + (size_t)nd * 256 + n) =
                        pack2bf(mine, partner);
                }
            }
        }
    }
}

// ---------------- K2: edge gather + tiny MLP tail, HALF-RANGE ----------------
// Identical per-wave structure to R8 (measured best); processes quads
// [qbase, qend). 1024 blocks -> 4096 waves -> same ~18.3 quads/wave.
__global__ __launch_bounds__(256, 8) void edge_score_kernel(
    const unsigned short* __restrict__ uvs,
    const float* __restrict__ W2, const float* __restrict__ b2,
    const int* __restrict__ src, const int* __restrict__ dst,
    float* __restrict__ out, int qbase, int qend)
{
    const int t = threadIdx.x, lane = t & 63, wv = t >> 6;
    const int c = lane & 15;        // 16-B chunk within 128-col half
    const int g = lane >> 4;        // edge-in-quad 0..3

    bool idx64;
    {
        unsigned long long m =
            __ballot((src[2 * lane + 1] == 0) && (dst[2 * lane + 1] == 0));
        idx64 = (m == ~0ULL);
    }

    float w2f[8];
#pragma unroll
    for (int j = 0; j < 8; ++j) w2f[j] = W2[c * 8 + j];
    const float b2s = b2[0];

    const int gw = blockIdx.x * 4 + wv;
    const int NW = K2BLK * 4;                 // 4096 waves

    for (int q0 = qbase + gw; q0 < qend; q0 += 2 * NW) {
        const int q1  = q0 + NW;
        const int q1c = q1 < qend ? q1 : qend - 1;
        const int e0  = q0 * 4 + g;
        const int e1  = q1c * 4 + g;

        const int ns0 = idx64 ? src[2 * e0] : src[e0];
        const int nd0 = idx64 ? dst[2 * e0] : dst[e0];
        const int ns1 = idx64 ? src[2 * e1] : src[e1];
        const int nd1 = idx64 ? dst[2 * e1] : dst[e1];

        const uint4 qu0 = *(const uint4*)(uvs + (size_t)ns0 * 256 + c * 8);
        const uint4 qv0 = *(const uint4*)(uvs + (size_t)nd0 * 256 + 128 + c * 8);
        const uint4 qu1 = *(const uint4*)(uvs + (size_t)ns1 * 256 + c * 8);
        const uint4 qv1 = *(const uint4*)(uvs + (size_t)nd1 * 256 + 128 + c * 8);

#pragma unroll
        for (int half = 0; half < 2; ++half) {
            const uint4 qu = half ? qu1 : qu0;
            const uint4 qv = half ? qv1 : qv0;
            float p = 0.0f;
#pragma unroll
            for (int j = 0; j < 4; ++j) {
                const unsigned int uw = j == 0 ? qu.x : j == 1 ? qu.y
                                      : j == 2 ? qu.z : qu.w;
                const unsigned int vw = j == 0 ? qv.x : j == 1 ? qv.y
                                      : j == 2 ? qv.z : qv.w;
                float slo = __uint_as_float(uw << 16)
                          + __uint_as_float(vw << 16);
                float shi = __uint_as_float(uw & 0xFFFF0000u)
                          + __uint_as_float(vw & 0xFFFF0000u);
                slo = slo > 0.0f ? slo : 0.0f;
                shi = shi > 0.0f ? shi : 0.0f;
                p = fmaf(slo, w2f[2 * j], p);
                p = fmaf(shi, w2f[2 * j + 1], p);
            }
            p += __shfl_xor(p, 1);
            p += __shfl_xor(p, 2);
            p += __shfl_xor(p, 4);
            p += __shfl_xor(p, 8);

            if (c == 0 && (half == 0 || q1 < qend)) {
                const int e = half ? e1 : e0;
                out[e] = 1.0f / (1.0f + __expf(-(p + b2s)));
            }
        }
    }
}

// ---------------- fallback (proven single-kernel) ----------------
__global__ __launch_bounds__(256, 1) void edge_mlp_fallback(
    const float* __restrict__ h,  const float* __restrict__ W1,
    const float* __restrict__ b1, const float* __restrict__ W2,
    const float* __restrict__ b2, const int* __restrict__ src,
    const int* __restrict__ dst,  float* __restrict__ out)
{
    __shared__ unsigned char smem[65536];
    const int t = threadIdx.x, lane = t & 63, wv = t >> 6;
    const int l31 = lane & 31, l5 = lane >> 5;
    bool idx64;
    {
        unsigned long long m =
            __ballot((src[2 * lane + 1] == 0) && (dst[2 * lane + 1] == 0));
        idx64 = (m == ~0ULL);
    }
    for (int task = t; task < 4096; task += 256) {
        int n = task & 127, slot = task >> 7;
        const float* wp = W1 + (slot * 8) * HID + n;
        bf16x8 v;
#pragma unroll
        for (int j = 0; j < 8; ++j) v[j] = (__bf16)wp[j * HID];
        *(bf16x8*)(smem + n * 512 + ((slot * 16) ^ ((n & 31) << 4))) = v;
    }
    float b1v[4], w2v[4];
#pragma unroll
    for (int ct = 0; ct < 4; ++ct) {
        int n = ct * 32 + l31;
        b1v[ct] = b1[n]; w2v[ct] = W2[n];
    }
    const float b2s = b2[0];
    __syncthreads();
    const int swz = l31 << 4;
    const int gw = blockIdx.x * 4 + wv;
    for (int tile = gw; tile < NEDGE / 32; tile += 512 * 4) {
        const int e = tile * 32 + l31;
        const long long ns = idx64 ? (long long)src[2 * e] : (long long)src[e];
        const long long nd = idx64 ? (long long)dst[2 * e] : (long long)dst[e];
        const float* hs = h + ns * HID + l5 * 8;
        const float* hd = h + nd * HID + l5 * 8;
        f32x16 acc[4];
#pragma unroll
        for (int ct = 0; ct < 4; ++ct)
#pragma unroll
            for (int r = 0; r < 16; ++r) acc[ct][r] = 0.0f;
#pragma unroll
        for (int ks = 0; ks < 16; ++ks) {
            const float* p = (ks < 8) ? (hs + ks * 16) : (hd + (ks - 8) * 16);
            float4 f0 = *(const float4*)p;
            float4 f1 = *(const float4*)(p + 4);
            bf16x8 af;
            af[0] = (__bf16)f0.x; af[1] = (__bf16)f0.y;
            af[2] = (__bf16)f0.z; af[3] = (__bf16)f0.w;
            af[4] = (__bf16)f1.x; af[5] = (__bf16)f1.y;
            af[6] = (__bf16)f1.z; af[7] = (__bf16)f1.w;
            const int coff = ks * 32 + l5 * 16;
#pragma unroll
            for (int ct = 0; ct < 4; ++ct) {
                const int n = ct * 32 + l31;
                bf16x8 bfg = *(const bf16x8*)(smem + n * 512 + (coff ^ swz));
                acc[ct] = __builtin_amdgcn_mfma_f32_32x32x16_bf16(af, bfg,
                                                                  acc[ct], 0, 0, 0);
            }
        }
        float p[16];
#pragma unroll
        for (int r = 0; r < 16; ++r) p[r] = 0.0f;
#pragma unroll
        for (int ct = 0; ct < 4; ++ct)
#pragma unroll
            for (int r = 0; r < 16; ++r) {
                float v = acc[ct][r] + b1v[ct];
                v = v > 0.0f ? v : 0.0f;
                p[r] += v * w2v[ct];
            }
#pragma unroll
        for (int r = 0; r < 16; ++r) {
            p[r] += __shfl_xor(p[r], 1);  p[r] += __shfl_xor(p[r], 2);
            p[r] += __shfl_xor(p[r], 4);  p[r] += __shfl_xor(p[r], 8);
            p[r] += __shfl_xor(p[r], 16);
        }
        if (l31 == 0) {
#pragma unroll
            for (int g = 0; g < 4; ++g) {
                const int e0 = tile * 32 + g * 8 + l5 * 4;
                float4 o4;
                o4.x = 1.0f / (1.0f + __expf(-(p[4 * g + 0] + b2s)));
                o4.y = 1.0f / (1.0f + __expf(-(p[4 * g + 1] + b2s)));
                o4.z = 1.0f / (1.0f + __expf(-(p[4 * g + 2] + b2s)));
                o4.w = 1.0f / (1.0f + __expf(-(p[4 * g + 3] + b2s)));
                *(float4*)(out + e0) = o4;
            }
        }
    }
}

extern "C" void kernel_launch(void* const* d_in, const int* in_sizes, int n_in,
                              void* d_out, int out_size, void* d_ws, size_t ws_size,
                              hipStream_t stream) {
    const float* h  = (const float*)d_in[0];
    const float* W1 = (const float*)d_in[1];
    const float* b1 = (const float*)d_in[2];
    const float* W2 = (const float*)d_in[3];
    const float* b2 = (const float*)d_in[4];
    const int* src  = (const int*)d_in[5];
    const int* dst  = (const int*)d_in[6];
    (void)in_sizes; (void)n_in; (void)out_size;

    if (ws_size >= UVBYTES) {
        unsigned short* uvs = (unsigned short*)d_ws;
        node_gemm_kernel<<<K1BLK, 256, 0, stream>>>(h, W1, b1, uvs);
        edge_score_kernel<<<K2BLK, 256, 0, stream>>>(uvs, W2, b2, src, dst,
                                                     (float*)d_out, 0, NQ_HALF);
        edge_score_kernel<<<K2BLK, 256, 0, stream>>>(uvs, W2, b2, src, dst,
                                                     (float*)d_out, NQ_HALF,
                                                     NQ_ALL);
    } else {
        edge_mlp_fallback<<<512, 256, 0, stream>>>(h, W1, b1, W2, b2, src, dst,
                                                   (float*)d_out);
    }
}

// Round 17
// 67.101 us; speedup vs baseline: 3.2526x; 1.1843x over previous
//
#include <hip/hip_runtime.h>
#include <hip/hip_bf16.h>

// score = sigmoid(relu([h[src]|h[dst]]@W1 + b1) @ W2 + b2)
// R17: R16 with the LDS geometry bug FIXED. The h tile is 32 rows x 128 k
// = 256 B/row bf16 = 8 KB total; R16 used a 512-B row stride (copied from
// the 256-k edge tile of R1-R7) in BOTH the staging write and the fragment
// read -> OOB LDS writes -> absmax 0.227. Row stride corrected to 256.
//   K0: W1 -> frag table (R9 exact).
//   K1: dense-staged h tile (contiguous 16 KB/block stream) -> swizzled LDS
//       -> ds_read_b128 A-frags; B-frags from frag table (16 B/lane, L2-hot).
//       1563 blocks, 4 waves = (colhalf x ctpair), acc = 2 x f32x16, (256,2).
//   K2: R8 exact (42.6 us random-gather wall).

#define HID    128
#define NNODE  50000
#define NEDGE  600000
#define NGRP   ((NNODE + 31) / 32)       // 1563 node groups of 32
#define K2BLK  2048
#define UVBYTES ((size_t)NNODE * 256 * 2)   // 25.6 MB
#define WTFRAG_OFF UVBYTES                  // frag-ordered W1T, 64 KB

typedef __attribute__((ext_vector_type(8)))  __bf16 bf16x8;
typedef __attribute__((ext_vector_type(16))) float  f32x16;

static __device__ __forceinline__ unsigned int pack2bf(float a, float b) {
    unsigned int ua = __float_as_uint(a);
    unsigned int ub = __float_as_uint(b);
    ua = (ua + 0x7FFFu + ((ua >> 16) & 1u)) >> 16;
    ub = (ub + 0x7FFFu + ((ub >> 16) & 1u)) >> 16;
    return (ub << 16) | (ua & 0xFFFFu);
}

// ---------------- K0: W1 -> bf16 fragment-ordered table (R9 exact) ----------
__global__ __launch_bounds__(256, 1) void w1_frag_kernel(
    const float* __restrict__ W1, unsigned short* __restrict__ w1tf)
{
    const int T = blockIdx.x * 256 + threadIdx.x;   // 4096 threads
    const int l31  = T & 31;
    const int FIDX = T >> 5;
    const int l5 = FIDX & 1, ks = (FIDX >> 1) & 7;
    const int ct = (FIDX >> 4) & 3, colhalf = FIDX >> 6;
    const int kb = colhalf * 128 + ks * 16 + l5 * 8;
    const int n  = ct * 32 + l31;
    bf16x8 v;
#pragma unroll
    for (int j = 0; j < 8; ++j) v[j] = (__bf16)W1[(kb + j) * HID + n];
    *(bf16x8*)(w1tf + (size_t)T * 8) = v;
}

// ---------------- K1: node GEMM, dense-staged h tile ----------------
__global__ __launch_bounds__(256, 2) void node_gemm_kernel(
    const float* __restrict__ h, const unsigned short* __restrict__ w1tf,
    const float* __restrict__ b1, unsigned short* __restrict__ uvs)
{
    // A tile: 32 rows x 128 bf16 = 256 B/row, 8 KB. 16B slots (s=0..15)
    // XOR-swizzled by (row&7)<<4 (bijective within the 256-B row).
    __shared__ unsigned char smem[8192];

    const int t = threadIdx.x, lane = t & 63, wv = t >> 6;
    const int l31 = lane & 31, l5 = lane >> 5;
    const int group = blockIdx.x;

    // ---- stage h tile: DENSE. task tau: row r=tau>>4, slot s=tau&15.
    // non-tail read addr = base + tau*8 floats (contiguous across block).
    {
        const float* hb = h + (size_t)group * 32 * HID;
        const bool tail = (group == NGRP - 1);
#pragma unroll
        for (int it = 0; it < 2; ++it) {
            const int tau = it * 256 + t;
            const int r = tau >> 4, s = tau & 15;
            const float* src_;
            if (tail) {
                const int node = group * 32 + r;
                const int rc = (node < NNODE) ? r : (NNODE - 1 - group * 32);
                src_ = hb + rc * HID + s * 8;
            } else {
                src_ = hb + tau * 8;
            }
            float4 f0 = *(const float4*)src_;
            float4 f1 = *(const float4*)(src_ + 4);
            bf16x8 v;
            v[0] = (__bf16)f0.x; v[1] = (__bf16)f0.y;
            v[2] = (__bf16)f0.z; v[3] = (__bf16)f0.w;
            v[4] = (__bf16)f1.x; v[5] = (__bf16)f1.y;
            v[6] = (__bf16)f1.z; v[7] = (__bf16)f1.w;
            *(bf16x8*)(smem + r * 256 + ((s * 16) ^ ((r & 7) << 4))) = v;
        }
    }
    __syncthreads();

    const int colhalf = wv >> 1;            // 0 -> u cols, 1 -> v cols
    const int ctpair  = wv & 1;             // 64-col slice within the half

    float b1v[2];
#pragma unroll
    for (int cc = 0; cc < 2; ++cc)
        b1v[cc] = (colhalf == 0) ? b1[(ctpair * 2 + cc) * 32 + l31] : 0.0f;

    f32x16 acc[2];
#pragma unroll
    for (int cc = 0; cc < 2; ++cc)
#pragma unroll
        for (int r = 0; r < 16; ++r) acc[cc][r] = 0.0f;

    const int abase = l31 * 256;            // FIXED: 256-B rows (was 512)
    const int aswz  = (l31 & 7) << 4;

#pragma unroll
    for (int ks = 0; ks < 8; ++ks) {
        // A-frag: row=l31, k = ks*16 + l5*8 + j -> byte off ks*32 + l5*16
        bf16x8 af = *(const bf16x8*)(smem + abase +
                                     ((ks * 32 + l5 * 16) ^ aswz));
#pragma unroll
        for (int cc = 0; cc < 2; ++cc) {
            const int fidx = ((colhalf * 4 + ctpair * 2 + cc) * 8 + ks) * 2 + l5;
            bf16x8 bfg = *(const bf16x8*)(w1tf + (size_t)fidx * 256 + l31 * 8);
            acc[cc] = __builtin_amdgcn_mfma_f32_32x32x16_bf16(af, bfg,
                                                              acc[cc], 0, 0, 0);
        }
    }

    // store: C row rr=(r&3)+8*(r>>2)+4*l5 (node), col = colhalf*128 +
    // (ctpair*2+cc)*32 + l31. pair-pack -> 4B stores, 2 lines/instr.
#pragma unroll
    for (int cc = 0; cc < 2; ++cc) {
#pragma unroll
        for (int r = 0; r < 16; ++r) {
            float mine = acc[cc][r] + b1v[cc];
            float partner = __shfl_xor(mine, 1);
            if (!(l31 & 1)) {
                const int rr = (r & 3) + 8 * (r >> 2) + 4 * l5;
                const int nd = group * 32 + rr;
                if (nd < NNODE) {
                    const int n = colhalf * 128 + (ctpair * 2 + cc) * 32 + l31;
                    *(unsigned int*)(uvs + (size_t)nd * 256 + n) =
                        pack2bf(mine, partner);
                }
            }
        }
    }
}

// ---------------- K2: edge gather + tiny MLP tail (R8 exact) ----------------
__global__ __launch_bounds__(256, 8) void edge_score_kernel(
    const unsigned short* __restrict__ uvs,
    const float* __restrict__ W2, const float* __restrict__ b2,
    const int* __restrict__ src, const int* __restrict__ dst,
    float* __restrict__ out)
{
    const int t = threadIdx.x, lane = t & 63, wv = t >> 6;
    const int c = lane & 15;        // 16-B chunk within 128-col half
    const int g = lane >> 4;        // edge-in-quad 0..3

    bool idx64;
    {
        unsigned long long m =
            __ballot((src[2 * lane + 1] == 0) && (dst[2 * lane + 1] == 0));
        idx64 = (m == ~0ULL);
    }

    float w2f[8];
#pragma unroll
    for (int j = 0; j < 8; ++j) w2f[j] = W2[c * 8 + j];
    const float b2s = b2[0];

    const int gw = blockIdx.x * 4 + wv;
    const int NW = K2BLK * 4;
    const int NQ = NEDGE / 4;

    for (int q0 = gw; q0 < NQ; q0 += 2 * NW) {
        const int q1  = q0 + NW;
        const int q1c = q1 < NQ ? q1 : NQ - 1;
        const int e0  = q0 * 4 + g;
        const int e1  = q1c * 4 + g;

        const int ns0 = idx64 ? src[2 * e0] : src[e0];
        const int nd0 = idx64 ? dst[2 * e0] : dst[e0];
        const int ns1 = idx64 ? src[2 * e1] : src[e1];
        const int nd1 = idx64 ? dst[2 * e1] : dst[e1];

        const uint4 qu0 = *(const uint4*)(uvs + (size_t)ns0 * 256 + c * 8);
        const uint4 qv0 = *(const uint4*)(uvs + (size_t)nd0 * 256 + 128 + c * 8);
        const uint4 qu1 = *(const uint4*)(uvs + (size_t)ns1 * 256 + c * 8);
        const uint4 qv1 = *(const uint4*)(uvs + (size_t)nd1 * 256 + 128 + c * 8);

#pragma unroll
        for (int half = 0; half < 2; ++half) {
            const uint4 qu = half ? qu1 : qu0;
            const uint4 qv = half ? qv1 : qv0;
            float p = 0.0f;
#pragma unroll
            for (int j = 0; j < 4; ++j) {
                const unsigned int uw = j == 0 ? qu.x : j == 1 ? qu.y
                                      : j == 2 ? qu.z : qu.w;
                const unsigned int vw = j == 0 ? qv.x : j == 1 ? qv.y
                                      : j == 2 ? qv.z : qv.w;
                float slo = __uint_as_float(uw << 16)
                          + __uint_as_float(vw << 16);
                float shi = __uint_as_float(uw & 0xFFFF0000u)
                          + __uint_as_float(vw & 0xFFFF0000u);
                slo = slo > 0.0f ? slo : 0.0f;
                shi = shi > 0.0f ? shi : 0.0f;
                p = fmaf(slo, w2f[2 * j], p);
                p = fmaf(shi, w2f[2 * j + 1], p);
            }
            p += __shfl_xor(p, 1);
            p += __shfl_xor(p, 2);
            p += __shfl_xor(p, 4);
            p += __shfl_xor(p, 8);

            if (c == 0 && (half == 0 || q1 < NQ)) {
                const int e = half ? e1 : e0;
                out[e] = 1.0f / (1.0f + __expf(-(p + b2s)));
            }
        }
    }
}

// ---------------- fallback (proven single-kernel) ----------------
__global__ __launch_bounds__(256, 1) void edge_mlp_fallback(
    const float* __restrict__ h,  const float* __restrict__ W1,
    const float* __restrict__ b1, const float* __restrict__ W2,
    const float* __restrict__ b2, const int* __restrict__ src,
    const int* __restrict__ dst,  float* __restrict__ out)
{
    __shared__ unsigned char smem[65536];
    const int t = threadIdx.x, lane = t & 63, wv = t >> 6;
    const int l31 = lane & 31, l5 = lane >> 5;
    bool idx64;
    {
        unsigned long long m =
            __ballot((src[2 * lane + 1] == 0) && (dst[2 * lane + 1] == 0));
        idx64 = (m == ~0ULL);
    }
    for (int task = t; task < 4096; task += 256) {
        int n = task & 127, slot = task >> 7;
        const float* wp = W1 + (slot * 8) * HID + n;
        bf16x8 v;
#pragma unroll
        for (int j = 0; j < 8; ++j) v[j] = (__bf16)wp[j * HID];
        *(bf16x8*)(smem + n * 512 + ((slot * 16) ^ ((n & 31) << 4))) = v;
    }
    float b1v[4], w2v[4];
#pragma unroll
    for (int ct = 0; ct < 4; ++ct) {
        int n = ct * 32 + l31;
        b1v[ct] = b1[n]; w2v[ct] = W2[n];
    }
    const float b2s = b2[0];
    __syncthreads();
    const int swz = l31 << 4;
    const int gw = blockIdx.x * 4 + wv;
    for (int tile = gw; tile < NEDGE / 32; tile += 512 * 4) {
        const int e = tile * 32 + l31;
        const long long ns = idx64 ? (long long)src[2 * e] : (long long)src[e];
        const long long nd = idx64 ? (long long)dst[2 * e] : (long long)dst[e];
        const float* hs = h + ns * HID + l5 * 8;
        const float* hd = h + nd * HID + l5 * 8;
        f32x16 acc[4];
#pragma unroll
        for (int ct = 0; ct < 4; ++ct)
#pragma unroll
            for (int r = 0; r < 16; ++r) acc[ct][r] = 0.0f;
#pragma unroll
        for (int ks = 0; ks < 16; ++ks) {
            const float* p = (ks < 8) ? (hs + ks * 16) : (hd + (ks - 8) * 16);
            float4 f0 = *(const float4*)p;
            float4 f1 = *(const float4*)(p + 4);
            bf16x8 af;
            af[0] = (__bf16)f0.x; af[1] = (__bf16)f0.y;
            af[2] = (__bf16)f0.z; af[3] = (__bf16)f0.w;
            af[4] = (__bf16)f1.x; af[5] = (__bf16)f1.y;
            af[6] = (__bf16)f1.z; af[7] = (__bf16)f1.w;
            const int coff = ks * 32 + l5 * 16;
#pragma unroll
            for (int ct = 0; ct < 4; ++ct) {
                const int n = ct * 32 + l31;
                bf16x8 bfg = *(const bf16x8*)(smem + n * 512 + (coff ^ swz));
                acc[ct] = __builtin_amdgcn_mfma_f32_32x32x16_bf16(af, bfg,
                                                                  acc[ct], 0, 0, 0);
            }
        }
        float p[16];
#pragma unroll
        for (int r = 0; r < 16; ++r) p[r] = 0.0f;
#pragma unroll
        for (int ct = 0; ct < 4; ++ct)
#pragma unroll
            for (int r = 0; r < 16; ++r) {
                float v = acc[ct][r] + b1v[ct];
                v = v > 0.0f ? v : 0.0f;
                p[r] += v * w2v[ct];
            }
#pragma unroll
        for (int r = 0; r < 16; ++r) {
            p[r] += __shfl_xor(p[r], 1);  p[r] += __shfl_xor(p[r], 2);
            p[r] += __shfl_xor(p[r], 4);  p[r] += __shfl_xor(p[r], 8);
            p[r] += __shfl_xor(p[r], 16);
        }
        if (l31 == 0) {
#pragma unroll
            for (int g = 0; g < 4; ++g) {
                const int e0 = tile * 32 + g * 8 + l5 * 4;
                float4 o4;
                o4.x = 1.0f / (1.0f + __expf(-(p[4 * g + 0] + b2s)));
                o4.y = 1.0f / (1.0f + __expf(-(p[4 * g + 1] + b2s)));
                o4.z = 1.0f / (1.0f + __expf(-(p[4 * g + 2] + b2s)));
                o4.w = 1.0f / (1.0f + __expf(-(p[4 * g + 3] + b2s)));
                *(float4*)(out + e0) = o4;
            }
        }
    }
}

extern "C" void kernel_launch(void* const* d_in, const int* in_sizes, int n_in,
                              void* d_out, int out_size, void* d_ws, size_t ws_size,
                              hipStream_t stream) {
    const float* h  = (const float*)d_in[0];
    const float* W1 = (const float*)d_in[1];
    const float* b1 = (const float*)d_in[2];
    const float* W2 = (const float*)d_in[3];
    const float* b2 = (const float*)d_in[4];
    const int* src  = (const int*)d_in[5];
    const int* dst  = (const int*)d_in[6];
    (void)in_sizes; (void)n_in; (void)out_size;

    const size_t need = WTFRAG_OFF + 65536;
    if (ws_size >= need) {
        unsigned short* uvs  = (unsigned short*)d_ws;
        unsigned short* w1tf = (unsigned short*)((char*)d_ws + WTFRAG_OFF);
        w1_frag_kernel<<<16, 256, 0, stream>>>(W1, w1tf);
        node_gemm_kernel<<<NGRP, 256, 0, stream>>>(h, w1tf, b1, uvs);
        edge_score_kernel<<<K2BLK, 256, 0, stream>>>(uvs, W2, b2, src, dst,
                                                     (float*)d_out);
    } else {
        edge_mlp_fallback<<<512, 256, 0, stream>>>(h, W1, b1, W2, b2, src, dst,
                                                   (float*)d_out);
    }
}